// Round 1
// baseline (972.406 us; speedup 1.0000x reference)
//
#include <hip/hip_runtime.h>
#include <hip/hip_bf16.h>
#include <cstdint>
#include <cstddef>

// ---------------- types ----------------
typedef _Float16 f16;
typedef _Float16 f16x4 __attribute__((ext_vector_type(4)));
typedef _Float16 f16x8 __attribute__((ext_vector_type(8)));
typedef float f32x4 __attribute__((ext_vector_type(4)));

#define GPTR(p) ((const __attribute__((address_space(1))) void*)(p))
#define LPTR(p) ((__attribute__((address_space(3))) void*)(p))

// Problem constants
#define T_TOK 8192
#define H_DIM 1024
#define I_DIM 512
#define N_EXP 16
#define TOPK 2
#define NSLOT (T_TOK * TOPK)   // 16384, always exact (top-2 distinct experts)

// ---------------- f32 -> f16 cast (4 elems/thread) ----------------
__global__ void cast4(const float* __restrict__ in, f16* __restrict__ out, int n4) {
    int i = blockIdx.x * blockDim.x + threadIdx.x;
    if (i >= n4) return;
    float4 v = ((const float4*)in)[i];
    f16x4 o = { (f16)v.x, (f16)v.y, (f16)v.z, (f16)v.w };
    *(f16x4*)(out + (size_t)i * 4) = o;
}

__global__ void zero_counts(int* counts) { counts[threadIdx.x] = 0; }

// ---------------- router: one wave per token ----------------
// lane = e(0..15) x seg(0..3); each lane dots 256 of H for expert e.
__global__ void router_kernel(const float* __restrict__ x, const float* __restrict__ gw,
                              int* __restrict__ sel, float* __restrict__ rw,
                              int* __restrict__ counts) {
    int t = blockIdx.x * 4 + (threadIdx.x >> 6);
    int lane = threadIdx.x & 63;
    int e = lane & 15, seg = lane >> 4;
    const float4* xv = (const float4*)(x + (size_t)t * H_DIM + seg * 256);
    const float4* gv = (const float4*)(gw + (size_t)e * H_DIM + seg * 256);
    float acc = 0.f;
#pragma unroll 8
    for (int i = 0; i < 64; i++) {
        float4 a = xv[i], b = gv[i];
        acc += a.x * b.x + a.y * b.y + a.z * b.z + a.w * b.w;
    }
    acc += __shfl_down(acc, 32);
    acc += __shfl_down(acc, 16);   // lanes 0..15 now hold the 16 logits
    // all lanes track top-2 (uniform shfl participation); ties: first index wins top slot
    float best = -1e30f, sec = -1e30f; int bi = 0, si = 0;
    for (int j = 0; j < 16; j++) {
        float lj = __shfl(acc, j);
        if (lj > best) { sec = best; si = bi; best = lj; bi = j; }
        else if (lj > sec) { sec = lj; si = j; }
    }
    if (lane == 0) {
        // renormalized top-2 softmax weight depends only on the two top logits
        float w1 = 1.f / (1.f + __expf(sec - best));
        sel[t * 2] = bi; sel[t * 2 + 1] = si;
        rw[t * 2] = w1;  rw[t * 2 + 1] = 1.f - w1;
        atomicAdd(&counts[bi], 1);
        atomicAdd(&counts[si], 1);
    }
}

__global__ void prefix_kernel(const int* __restrict__ counts, int* __restrict__ offsets,
                              int* __restrict__ cursors) {
    if (threadIdx.x == 0) {
        int s = 0;
        for (int e = 0; e < N_EXP; e++) { offsets[e] = s; cursors[e] = s; s += counts[e]; }
        offsets[N_EXP] = s;   // always 16384
    }
}

__global__ void scatter_kernel(const int* __restrict__ sel, const float* __restrict__ rw,
                               int* __restrict__ cursors, int* __restrict__ btok,
                               float* __restrict__ bw) {
    int t = blockIdx.x * blockDim.x + threadIdx.x;
    if (t >= T_TOK) return;
#pragma unroll
    for (int k = 0; k < TOPK; k++) {
        int e = sel[t * 2 + k];
        int pos = atomicAdd(&cursors[e], 1);
        btok[pos] = t;
        bw[pos] = rw[t * 2 + k];
    }
}

// ---------------- gate_up GEMM: GU[slot, 0:1024] = X[row] @ W_e^T + bias_e ----------------
// m97 recipe: 128x128 tile, BK=32, 4 waves (2x2 of 64x64), mfma 16x16x32 f16,
// global_load_lds width=16 into unpadded [128][32] LDS tiles.
__global__ __launch_bounds__(256) void gemm_gateup(
    const f16* __restrict__ X,        // [T,1024] f16
    const f16* __restrict__ W,        // [E,1024,1024] (or [1024,1024], e forced 0 by grid)
    const float* __restrict__ bias,   // [E,1024] (or [1024])
    f16* __restrict__ GU,             // [slots,1024]
    const int* __restrict__ offsets,  // null => shared-expert mode (identity gather)
    const int* __restrict__ btok,
    int Mfixed) {
    constexpr int K = H_DIM;
    const int e  = blockIdx.z;
    const int m0 = blockIdx.x * 128;
    const int n0 = blockIdx.y * 128;
    int base = 0, M = Mfixed;
    if (offsets) { base = offsets[e]; M = offsets[e + 1] - base; }
    if (m0 >= M) return;

    const f16* Wb  = W + (size_t)e * 1024 * K;
    const float* bb = bias + (size_t)e * 1024;

    __shared__ f16 As[128 * 32];
    __shared__ f16 Bs[128 * 32];

    const int tid  = threadIdx.x;
    const int wave = tid >> 6;
    const int lane = tid & 63;
    const int srow = lane >> 2;          // 0..15
    const int scol = (lane & 3) * 8;     // 0,8,16,24

    // staging: wave w fills rows [w*32, w*32+32) of both tiles (two 16-row chunks each)
    int ar0 = m0 + wave * 32 + srow;
    int ar1 = ar0 + 16;
    int r0 = min(ar0, M - 1), r1 = min(ar1, M - 1);
    size_t g0 = offsets ? (size_t)btok[base + r0] : (size_t)r0;
    size_t g1 = offsets ? (size_t)btok[base + r1] : (size_t)r1;
    const f16* ap0 = X + g0 * K + scol;
    const f16* ap1 = X + g1 * K + scol;
    const f16* bp0 = Wb + (size_t)(n0 + wave * 32 + srow) * K + scol;
    const f16* bp1 = bp0 + (size_t)16 * K;
    f16* la0 = &As[(wave * 32) * 32];
    f16* la1 = &As[(wave * 32 + 16) * 32];
    f16* lb0 = &Bs[(wave * 32) * 32];
    f16* lb1 = &Bs[(wave * 32 + 16) * 32];

    const int wm = (wave >> 1) * 64;
    const int wn = (wave & 1) * 64;
    const int qm = lane & 15;
    const int quad = lane >> 4;

    f32x4 acc[4][4];
#pragma unroll
    for (int i = 0; i < 4; i++)
#pragma unroll
        for (int j = 0; j < 4; j++) acc[i][j] = (f32x4){0.f, 0.f, 0.f, 0.f};

    for (int k0 = 0; k0 < K; k0 += 32) {
        __builtin_amdgcn_global_load_lds(GPTR(ap0), LPTR(la0), 16, 0, 0);
        __builtin_amdgcn_global_load_lds(GPTR(ap1), LPTR(la1), 16, 0, 0);
        __builtin_amdgcn_global_load_lds(GPTR(bp0), LPTR(lb0), 16, 0, 0);
        __builtin_amdgcn_global_load_lds(GPTR(bp1), LPTR(lb1), 16, 0, 0);
        ap0 += 32; ap1 += 32; bp0 += 32; bp1 += 32;
        __syncthreads();   // drains vmcnt -> tiles ready
        f16x8 af[4], bfr[4];
#pragma unroll
        for (int i = 0; i < 4; i++) af[i]  = *(const f16x8*)&As[(wm + i * 16 + qm) * 32 + quad * 8];
#pragma unroll
        for (int j = 0; j < 4; j++) bfr[j] = *(const f16x8*)&Bs[(wn + j * 16 + qm) * 32 + quad * 8];
#pragma unroll
        for (int i = 0; i < 4; i++)
#pragma unroll
            for (int j = 0; j < 4; j++)
                acc[i][j] = __builtin_amdgcn_mfma_f32_16x16x32_f16(af[i], bfr[j], acc[i][j], 0, 0, 0);
        __syncthreads();   // all reads done before next stage overwrites
    }

    // C/D mapping: col = lane&15, row = quad*4 + reg  [verified m89]
#pragma unroll
    for (int i = 0; i < 4; i++) {
#pragma unroll
        for (int j = 0; j < 4; j++) {
            const int col = n0 + wn + j * 16 + qm;
            const float bv = bb[col];
#pragma unroll
            for (int r = 0; r < 4; r++) {
                const int lr = wm + i * 16 + quad * 4 + r;
                const int m = m0 + lr;
                if (m < M) GU[(size_t)(base + m) * 1024 + col] = (f16)(acc[i][j][r] + bv);
            }
        }
    }
}

// ---------------- SiLU(g)*u, routing weight fused ----------------
__global__ void act_kernel(const f16* __restrict__ GU, const float* __restrict__ bw,
                           f16* __restrict__ ACT, int nslots) {
    int idx = blockIdx.x * blockDim.x + threadIdx.x;
    int s = idx >> 7;              // 128 threads per slot (512 cols / 4)
    int c = (idx & 127) * 4;
    if (s >= nslots) return;
    float scale = bw ? bw[s] : 1.f;
    const f16* g = GU + (size_t)s * 1024;
    f16x4 gv = *(const f16x4*)(g + c);
    f16x4 uv = *(const f16x4*)(g + 512 + c);
    f16x4 o;
#pragma unroll
    for (int r = 0; r < 4; r++) {
        float gg = (float)gv[r], uu = (float)uv[r];
        float sl = gg / (1.f + __expf(-gg));
        o[r] = (f16)(sl * uu * scale);
    }
    *(f16x4*)(ACT + (size_t)s * 512 + c) = o;
}

// ---------------- down GEMM: OUT[tok, 0:1024] (+)= ACT[slot] @ Wd_e^T ----------------
__global__ __launch_bounds__(256) void gemm_down(
    const f16* __restrict__ ACT,      // [slots,512] (contiguous rows per expert)
    const f16* __restrict__ W,        // [E,1024,512] (or [1024,512])
    float* __restrict__ OUT,          // [8192,1024]
    const int* __restrict__ offsets,  // null => shared mode: plain store
    const int* __restrict__ btok,
    int Mfixed) {
    constexpr int K = I_DIM;  // 512
    const int e  = blockIdx.z;
    const int m0 = blockIdx.x * 128;
    const int n0 = blockIdx.y * 128;
    int base = 0, M = Mfixed;
    if (offsets) { base = offsets[e]; M = offsets[e + 1] - base; }
    if (m0 >= M) return;

    const f16* Wb = W + (size_t)e * 1024 * K;

    __shared__ f16 As[128 * 32];
    __shared__ f16 Bs[128 * 32];

    const int tid  = threadIdx.x;
    const int wave = tid >> 6;
    const int lane = tid & 63;
    const int srow = lane >> 2;
    const int scol = (lane & 3) * 8;

    int ar0 = m0 + wave * 32 + srow;
    int ar1 = ar0 + 16;
    int r0 = min(ar0, M - 1), r1 = min(ar1, M - 1);
    const f16* ap0 = ACT + (size_t)(base + r0) * K + scol;
    const f16* ap1 = ACT + (size_t)(base + r1) * K + scol;
    const f16* bp0 = Wb + (size_t)(n0 + wave * 32 + srow) * K + scol;
    const f16* bp1 = bp0 + (size_t)16 * K;
    f16* la0 = &As[(wave * 32) * 32];
    f16* la1 = &As[(wave * 32 + 16) * 32];
    f16* lb0 = &Bs[(wave * 32) * 32];
    f16* lb1 = &Bs[(wave * 32 + 16) * 32];

    const int wm = (wave >> 1) * 64;
    const int wn = (wave & 1) * 64;
    const int qm = lane & 15;
    const int quad = lane >> 4;

    f32x4 acc[4][4];
#pragma unroll
    for (int i = 0; i < 4; i++)
#pragma unroll
        for (int j = 0; j < 4; j++) acc[i][j] = (f32x4){0.f, 0.f, 0.f, 0.f};

    for (int k0 = 0; k0 < K; k0 += 32) {
        __builtin_amdgcn_global_load_lds(GPTR(ap0), LPTR(la0), 16, 0, 0);
        __builtin_amdgcn_global_load_lds(GPTR(ap1), LPTR(la1), 16, 0, 0);
        __builtin_amdgcn_global_load_lds(GPTR(bp0), LPTR(lb0), 16, 0, 0);
        __builtin_amdgcn_global_load_lds(GPTR(bp1), LPTR(lb1), 16, 0, 0);
        ap0 += 32; ap1 += 32; bp0 += 32; bp1 += 32;
        __syncthreads();
        f16x8 af[4], bfr[4];
#pragma unroll
        for (int i = 0; i < 4; i++) af[i]  = *(const f16x8*)&As[(wm + i * 16 + qm) * 32 + quad * 8];
#pragma unroll
        for (int j = 0; j < 4; j++) bfr[j] = *(const f16x8*)&Bs[(wn + j * 16 + qm) * 32 + quad * 8];
#pragma unroll
        for (int i = 0; i < 4; i++)
#pragma unroll
            for (int j = 0; j < 4; j++)
                acc[i][j] = __builtin_amdgcn_mfma_f32_16x16x32_f16(af[i], bfr[j], acc[i][j], 0, 0, 0);
        __syncthreads();
    }

#pragma unroll
    for (int i = 0; i < 4; i++) {
#pragma unroll
        for (int j = 0; j < 4; j++) {
            const int col = n0 + wn + j * 16 + qm;
#pragma unroll
            for (int r = 0; r < 4; r++) {
                const int lr = wm + i * 16 + quad * 4 + r;
                const int m = m0 + lr;
                if (m < M) {
                    if (offsets) {
                        int tok = btok[base + m];
                        atomicAdd(&OUT[(size_t)tok * 1024 + col], acc[i][j][r]);
                    } else {
                        OUT[(size_t)m * 1024 + col] = acc[i][j][r];
                    }
                }
            }
        }
    }
}

// ---------------- host launch ----------------
extern "C" void kernel_launch(void* const* d_in, const int* in_sizes, int n_in,
                              void* d_out, int out_size, void* d_ws, size_t ws_size,
                              hipStream_t stream) {
    const float* x    = (const float*)d_in[0];   // [8192,1024]
    const float* gw   = (const float*)d_in[1];   // [16,1024]
    const float* wgu  = (const float*)d_in[2];   // [16,1024,1024]
    const float* bgu  = (const float*)d_in[3];   // [16,1024]
    const float* wd   = (const float*)d_in[4];   // [16,1024,512]
    const float* wsgu = (const float*)d_in[5];   // [1024,1024]
    const float* bsgu = (const float*)d_in[6];   // [1024]
    const float* wsd  = (const float*)d_in[7];   // [1024,512]
    float* out = (float*)d_out;

    char* ws = (char*)d_ws;
    size_t off = 0;
    auto take = [&](size_t b) { char* p = ws + off; off = (off + b + 255) & ~(size_t)255; return p; };
    f16* x_h    = (f16*)take((size_t)T_TOK * H_DIM * 2);
    f16* wgu_h  = (f16*)take((size_t)N_EXP * 1024 * H_DIM * 2);
    f16* wd_h   = (f16*)take((size_t)N_EXP * 1024 * I_DIM * 2);
    f16* wsgu_h = (f16*)take((size_t)1024 * H_DIM * 2);
    f16* wsd_h  = (f16*)take((size_t)1024 * I_DIM * 2);
    f16* gu_e   = (f16*)take((size_t)NSLOT * 1024 * 2);
    f16* gu_s   = (f16*)take((size_t)T_TOK * 1024 * 2);
    f16* act_e  = (f16*)take((size_t)NSLOT * I_DIM * 2);
    f16* act_s  = (f16*)take((size_t)T_TOK * I_DIM * 2);
    int*   sel    = (int*)take((size_t)NSLOT * 4);
    float* rw     = (float*)take((size_t)NSLOT * 4);
    int*   btok   = (int*)take((size_t)NSLOT * 4);
    float* bw     = (float*)take((size_t)NSLOT * 4);
    int*   counts = (int*)take(64);
    int*   offs   = (int*)take(68);
    int*   curs   = (int*)take(64);

    // 1) casts (element counts all multiples of 1024)
    cast4<<<8192,  256, 0, stream>>>(x,    x_h,    2097152);
    cast4<<<16384, 256, 0, stream>>>(wgu,  wgu_h,  4194304);
    cast4<<<8192,  256, 0, stream>>>(wd,   wd_h,   2097152);
    cast4<<<1024,  256, 0, stream>>>(wsgu, wsgu_h, 262144);
    cast4<<<512,   256, 0, stream>>>(wsd,  wsd_h,  131072);

    // 2) routing
    zero_counts<<<1, 16, 0, stream>>>(counts);
    router_kernel<<<T_TOK / 4, 256, 0, stream>>>(x, gw, sel, rw, counts);
    prefix_kernel<<<1, 64, 0, stream>>>(counts, offs, curs);
    scatter_kernel<<<T_TOK / 256, 256, 0, stream>>>(sel, rw, curs, btok, bw);

    // 3) gate_up GEMMs (shared: identity gather; experts: bucket gather)
    gemm_gateup<<<dim3(64, 8, 1),  256, 0, stream>>>(x_h, wsgu_h, bsgu, gu_s, nullptr, nullptr, T_TOK);
    gemm_gateup<<<dim3(64, 8, 16), 256, 0, stream>>>(x_h, wgu_h,  bgu,  gu_e, offs, btok, 0);

    // 4) SiLU*up (+routing weight for experts)
    act_kernel<<<T_TOK / 2,  256, 0, stream>>>(gu_s, nullptr, act_s, T_TOK);
    act_kernel<<<NSLOT / 2,  256, 0, stream>>>(gu_e, bw,      act_e, NSLOT);

    // 5) down GEMMs: shared plain-stores d_out (stream-ordered), experts atomicAdd on top
    gemm_down<<<dim3(64, 8, 1),  256, 0, stream>>>(act_s, wsd_h, out, nullptr, nullptr, T_TOK);
    gemm_down<<<dim3(64, 8, 16), 256, 0, stream>>>(act_e, wd_h,  out, offs, btok, 0);
}

// Round 2
// 759.926 us; speedup vs baseline: 1.2796x; 1.2796x over previous
//
#include <hip/hip_runtime.h>
#include <hip/hip_bf16.h>
#include <cstdint>
#include <cstddef>

// ---------------- types ----------------
typedef _Float16 f16;
typedef _Float16 f16x4 __attribute__((ext_vector_type(4)));
typedef _Float16 f16x8 __attribute__((ext_vector_type(8)));
typedef float f32x4 __attribute__((ext_vector_type(4)));

#define GPTR(p) ((const __attribute__((address_space(1))) void*)(p))
#define LPTR(p) ((__attribute__((address_space(3))) void*)(p))

// Problem constants
#define T_TOK 8192
#define H_DIM 1024
#define I_DIM 512
#define N_EXP 16          // routed experts; expert 16 = shared (weight 1.0, all tokens)
#define N_ALL 17
#define TOPK 2
#define NSLOT (T_TOK * TOPK)          // 16384 routed slots
#define NSLOT_ALL (NSLOT + T_TOK)     // 24576 incl. shared

// ---------------- f32 -> f16 cast (4 elems/thread) ----------------
__global__ void cast4(const float* __restrict__ in, f16* __restrict__ out, int n4) {
    int i = blockIdx.x * blockDim.x + threadIdx.x;
    if (i >= n4) return;
    float4 v = ((const float4*)in)[i];
    f16x4 o = { (f16)v.x, (f16)v.y, (f16)v.z, (f16)v.w };
    *(f16x4*)(out + (size_t)i * 4) = o;
}

__global__ void zero_counts(int* counts) { counts[threadIdx.x] = 0; }

// ---------------- router: one wave per token ----------------
__global__ void router_kernel(const float* __restrict__ x, const float* __restrict__ gw,
                              int* __restrict__ sel, float* __restrict__ rw,
                              int* __restrict__ counts) {
    int t = blockIdx.x * 4 + (threadIdx.x >> 6);
    int lane = threadIdx.x & 63;
    int e = lane & 15, seg = lane >> 4;
    const float4* xv = (const float4*)(x + (size_t)t * H_DIM + seg * 256);
    const float4* gv = (const float4*)(gw + (size_t)e * H_DIM + seg * 256);
    float acc = 0.f;
#pragma unroll 8
    for (int i = 0; i < 64; i++) {
        float4 a = xv[i], b = gv[i];
        acc += a.x * b.x + a.y * b.y + a.z * b.z + a.w * b.w;
    }
    acc += __shfl_down(acc, 32);
    acc += __shfl_down(acc, 16);   // lanes 0..15 hold the 16 logits
    float best = -1e30f, sec = -1e30f; int bi = 0, si = 0;
    for (int j = 0; j < 16; j++) {
        float lj = __shfl(acc, j);
        if (lj > best) { sec = best; si = bi; best = lj; bi = j; }
        else if (lj > sec) { sec = lj; si = j; }
    }
    if (lane == 0) {
        float w1 = 1.f / (1.f + __expf(sec - best));   // renormalized top-2 softmax
        sel[t * 2] = bi; sel[t * 2 + 1] = si;
        rw[t * 2] = w1;  rw[t * 2 + 1] = 1.f - w1;
        atomicAdd(&counts[bi], 1);
        atomicAdd(&counts[si], 1);
    }
}

__global__ void prefix_kernel(const int* __restrict__ counts, int* __restrict__ offsets,
                              int* __restrict__ cursors) {
    if (threadIdx.x == 0) {
        int s = 0;
        for (int e = 0; e < N_EXP; e++) { offsets[e] = s; cursors[e] = s; s += counts[e]; }
        offsets[N_EXP] = s;                 // 16384
        offsets[N_EXP + 1] = s + T_TOK;     // 24576 (shared bucket)
    }
}

// scatter routed slots + build the identity shared bucket; record slot pos per (t,k)
__global__ void scatter_kernel(const int* __restrict__ sel, const float* __restrict__ rw,
                               int* __restrict__ cursors, int* __restrict__ btok,
                               float* __restrict__ bw, int* __restrict__ pos) {
    int t = blockIdx.x * blockDim.x + threadIdx.x;
    if (t >= T_TOK) return;
#pragma unroll
    for (int k = 0; k < TOPK; k++) {
        int e = sel[t * 2 + k];
        int p = atomicAdd(&cursors[e], 1);
        btok[p] = t;
        bw[p] = rw[t * 2 + k];
        pos[t * 2 + k] = p;
    }
    btok[NSLOT + t] = t;     // shared bucket: identity
    bw[NSLOT + t] = 1.f;
}

// ---------------- gate_up GEMM: GU[slot, 0:1024] = X[btok[slot]] @ W_e^T + bias_e ----------
// m97 recipe: 128x128 tile, BK=32, 4 waves (2x2 of 64x64), mfma 16x16x32 f16,
// global_load_lds width=16 into unpadded [128][32] LDS tiles.
__global__ __launch_bounds__(256) void gemm_gateup(
    const f16* __restrict__ X,        // [T,1024] f16
    const f16* __restrict__ W,        // [17,1024,1024] f16
    const float* __restrict__ bias,   // [17,1024] f32
    f16* __restrict__ GU,             // [24576,1024] f16
    const int* __restrict__ offsets,  // [18]
    const int* __restrict__ btok) {
    constexpr int K = H_DIM;
    const int e  = blockIdx.z;
    const int m0 = blockIdx.x * 128;
    const int n0 = blockIdx.y * 128;
    const int base = offsets[e];
    const int M = offsets[e + 1] - base;
    if (m0 >= M) return;

    const f16* Wb   = W + (size_t)e * 1024 * K;
    const float* bb = bias + (size_t)e * 1024;

    __shared__ f16 As[128 * 32];
    __shared__ f16 Bs[128 * 32];

    const int tid  = threadIdx.x;
    const int wave = tid >> 6;
    const int lane = tid & 63;
    const int srow = lane >> 2;          // 0..15
    const int scol = (lane & 3) * 8;     // 0,8,16,24

    int ar0 = m0 + wave * 32 + srow;
    int ar1 = ar0 + 16;
    int r0 = min(ar0, M - 1), r1 = min(ar1, M - 1);
    const f16* ap0 = X + (size_t)btok[base + r0] * K + scol;
    const f16* ap1 = X + (size_t)btok[base + r1] * K + scol;
    const f16* bp0 = Wb + (size_t)(n0 + wave * 32 + srow) * K + scol;
    const f16* bp1 = bp0 + (size_t)16 * K;
    f16* la0 = &As[(wave * 32) * 32];
    f16* la1 = &As[(wave * 32 + 16) * 32];
    f16* lb0 = &Bs[(wave * 32) * 32];
    f16* lb1 = &Bs[(wave * 32 + 16) * 32];

    const int wm = (wave >> 1) * 64;
    const int wn = (wave & 1) * 64;
    const int qm = lane & 15;
    const int quad = lane >> 4;

    f32x4 acc[4][4];
#pragma unroll
    for (int i = 0; i < 4; i++)
#pragma unroll
        for (int j = 0; j < 4; j++) acc[i][j] = (f32x4){0.f, 0.f, 0.f, 0.f};

    for (int k0 = 0; k0 < K; k0 += 32) {
        __builtin_amdgcn_global_load_lds(GPTR(ap0), LPTR(la0), 16, 0, 0);
        __builtin_amdgcn_global_load_lds(GPTR(ap1), LPTR(la1), 16, 0, 0);
        __builtin_amdgcn_global_load_lds(GPTR(bp0), LPTR(lb0), 16, 0, 0);
        __builtin_amdgcn_global_load_lds(GPTR(bp1), LPTR(lb1), 16, 0, 0);
        ap0 += 32; ap1 += 32; bp0 += 32; bp1 += 32;
        __syncthreads();
        f16x8 af[4], bfr[4];
#pragma unroll
        for (int i = 0; i < 4; i++) af[i]  = *(const f16x8*)&As[(wm + i * 16 + qm) * 32 + quad * 8];
#pragma unroll
        for (int j = 0; j < 4; j++) bfr[j] = *(const f16x8*)&Bs[(wn + j * 16 + qm) * 32 + quad * 8];
#pragma unroll
        for (int i = 0; i < 4; i++)
#pragma unroll
            for (int j = 0; j < 4; j++)
                acc[i][j] = __builtin_amdgcn_mfma_f32_16x16x32_f16(af[i], bfr[j], acc[i][j], 0, 0, 0);
        __syncthreads();
    }

    // C/D mapping: col = lane&15, row = quad*4 + reg
#pragma unroll
    for (int i = 0; i < 4; i++) {
#pragma unroll
        for (int j = 0; j < 4; j++) {
            const int col = n0 + wn + j * 16 + qm;
            const float bv = bb[col];
#pragma unroll
            for (int r = 0; r < 4; r++) {
                const int lr = wm + i * 16 + quad * 4 + r;
                const int m = m0 + lr;
                if (m < M) GU[(size_t)(base + m) * 1024 + col] = (f16)(acc[i][j][r] + bv);
            }
        }
    }
}

// ---------------- SiLU(g)*u * routing_weight ----------------
__global__ void act_kernel(const f16* __restrict__ GU, const float* __restrict__ bw,
                           f16* __restrict__ ACT) {
    int idx = blockIdx.x * blockDim.x + threadIdx.x;
    int s = idx >> 7;              // 128 threads per slot (512 cols / 4)
    int c = (idx & 127) * 4;
    float scale = bw[s];
    const f16* g = GU + (size_t)s * 1024;
    f16x4 gv = *(const f16x4*)(g + c);
    f16x4 uv = *(const f16x4*)(g + 512 + c);
    f16x4 o;
#pragma unroll
    for (int r = 0; r < 4; r++) {
        float gg = (float)gv[r], uu = (float)uv[r];
        float sl = gg / (1.f + __expf(-gg));
        o[r] = (f16)(sl * uu * scale);
    }
    *(f16x4*)(ACT + (size_t)s * 512 + c) = o;
}

// ---------------- down GEMM: DOWN[slot, 0:1024] = ACT[slot] @ Wd_e^T (plain f16 store) ----
__global__ __launch_bounds__(256) void gemm_down(
    const f16* __restrict__ ACT,      // [24576,512]
    const f16* __restrict__ W,        // [17,1024,512]
    f16* __restrict__ DOWN,           // [24576,1024]
    const int* __restrict__ offsets) {
    constexpr int K = I_DIM;  // 512
    const int e  = blockIdx.z;
    const int m0 = blockIdx.x * 128;
    const int n0 = blockIdx.y * 128;
    const int base = offsets[e];
    const int M = offsets[e + 1] - base;
    if (m0 >= M) return;

    const f16* Wb = W + (size_t)e * 1024 * K;

    __shared__ f16 As[128 * 32];
    __shared__ f16 Bs[128 * 32];

    const int tid  = threadIdx.x;
    const int wave = tid >> 6;
    const int lane = tid & 63;
    const int srow = lane >> 2;
    const int scol = (lane & 3) * 8;

    int ar0 = m0 + wave * 32 + srow;
    int ar1 = ar0 + 16;
    int r0 = min(ar0, M - 1), r1 = min(ar1, M - 1);
    const f16* ap0 = ACT + (size_t)(base + r0) * K + scol;
    const f16* ap1 = ACT + (size_t)(base + r1) * K + scol;
    const f16* bp0 = Wb + (size_t)(n0 + wave * 32 + srow) * K + scol;
    const f16* bp1 = bp0 + (size_t)16 * K;
    f16* la0 = &As[(wave * 32) * 32];
    f16* la1 = &As[(wave * 32 + 16) * 32];
    f16* lb0 = &Bs[(wave * 32) * 32];
    f16* lb1 = &Bs[(wave * 32 + 16) * 32];

    const int wm = (wave >> 1) * 64;
    const int wn = (wave & 1) * 64;
    const int qm = lane & 15;
    const int quad = lane >> 4;

    f32x4 acc[4][4];
#pragma unroll
    for (int i = 0; i < 4; i++)
#pragma unroll
        for (int j = 0; j < 4; j++) acc[i][j] = (f32x4){0.f, 0.f, 0.f, 0.f};

    for (int k0 = 0; k0 < K; k0 += 32) {
        __builtin_amdgcn_global_load_lds(GPTR(ap0), LPTR(la0), 16, 0, 0);
        __builtin_amdgcn_global_load_lds(GPTR(ap1), LPTR(la1), 16, 0, 0);
        __builtin_amdgcn_global_load_lds(GPTR(bp0), LPTR(lb0), 16, 0, 0);
        __builtin_amdgcn_global_load_lds(GPTR(bp1), LPTR(lb1), 16, 0, 0);
        ap0 += 32; ap1 += 32; bp0 += 32; bp1 += 32;
        __syncthreads();
        f16x8 af[4], bfr[4];
#pragma unroll
        for (int i = 0; i < 4; i++) af[i]  = *(const f16x8*)&As[(wm + i * 16 + qm) * 32 + quad * 8];
#pragma unroll
        for (int j = 0; j < 4; j++) bfr[j] = *(const f16x8*)&Bs[(wn + j * 16 + qm) * 32 + quad * 8];
#pragma unroll
        for (int i = 0; i < 4; i++)
#pragma unroll
            for (int j = 0; j < 4; j++)
                acc[i][j] = __builtin_amdgcn_mfma_f32_16x16x32_f16(af[i], bfr[j], acc[i][j], 0, 0, 0);
        __syncthreads();
    }

#pragma unroll
    for (int i = 0; i < 4; i++) {
#pragma unroll
        for (int j = 0; j < 4; j++) {
            const int col = n0 + wn + j * 16 + qm;
#pragma unroll
            for (int r = 0; r < 4; r++) {
                const int lr = wm + i * 16 + quad * 4 + r;
                const int m = m0 + lr;
                if (m < M) DOWN[(size_t)(base + m) * 1024 + col] = (f16)acc[i][j][r];
            }
        }
    }
}

// ---------------- combine: out[t] = DOWN[16384+t] + DOWN[p1] + DOWN[p2] ----------------
__global__ void combine_kernel(const f16* __restrict__ DOWN, const int* __restrict__ pos,
                               float* __restrict__ OUT) {
    int idx = blockIdx.x * blockDim.x + threadIdx.x;
    int t = idx >> 8;             // 256 threads per token (1024 cols / 4)
    int c = (idx & 255) * 4;
    int p1 = pos[t * 2], p2 = pos[t * 2 + 1];
    f16x4 a = *(const f16x4*)(DOWN + (size_t)(NSLOT + t) * 1024 + c);
    f16x4 b = *(const f16x4*)(DOWN + (size_t)p1 * 1024 + c);
    f16x4 d = *(const f16x4*)(DOWN + (size_t)p2 * 1024 + c);
    float4 o;
    o.x = (float)a[0] + (float)b[0] + (float)d[0];
    o.y = (float)a[1] + (float)b[1] + (float)d[1];
    o.z = (float)a[2] + (float)b[2] + (float)d[2];
    o.w = (float)a[3] + (float)b[3] + (float)d[3];
    *(float4*)(OUT + (size_t)t * 1024 + c) = o;
}

// ---------------- host launch ----------------
extern "C" void kernel_launch(void* const* d_in, const int* in_sizes, int n_in,
                              void* d_out, int out_size, void* d_ws, size_t ws_size,
                              hipStream_t stream) {
    const float* x    = (const float*)d_in[0];   // [8192,1024]
    const float* gw   = (const float*)d_in[1];   // [16,1024]
    const float* wgu  = (const float*)d_in[2];   // [16,1024,1024]
    const float* bgu  = (const float*)d_in[3];   // [16,1024]
    const float* wd   = (const float*)d_in[4];   // [16,1024,512]
    const float* wsgu = (const float*)d_in[5];   // [1024,1024]
    const float* bsgu = (const float*)d_in[6];   // [1024]
    const float* wsd  = (const float*)d_in[7];   // [1024,512]
    float* out = (float*)d_out;

    char* ws = (char*)d_ws;
    size_t off = 0;
    auto take = [&](size_t b) { char* p = ws + off; off = (off + b + 255) & ~(size_t)255; return p; };
    f16* x_h    = (f16*)take((size_t)T_TOK * H_DIM * 2);
    f16* wguA   = (f16*)take((size_t)N_ALL * 1024 * H_DIM * 2);   // [17,1024,1024]
    f16* wdA    = (f16*)take((size_t)N_ALL * 1024 * I_DIM * 2);   // [17,1024,512]
    float* biasA = (float*)take((size_t)N_ALL * 1024 * 4);        // [17,1024]
    f16* gu     = (f16*)take((size_t)NSLOT_ALL * 1024 * 2);       // [24576,1024]
    f16* act    = (f16*)take((size_t)NSLOT_ALL * I_DIM * 2);      // [24576,512]
    f16* down   = gu;  // alias: gu is dead after act_kernel
    int*   sel    = (int*)take((size_t)NSLOT * 4);
    float* rw     = (float*)take((size_t)NSLOT * 4);
    int*   btok   = (int*)take((size_t)NSLOT_ALL * 4);
    float* bw     = (float*)take((size_t)NSLOT_ALL * 4);
    int*   pos    = (int*)take((size_t)NSLOT * 4);
    int*   counts = (int*)take(64);
    int*   offs   = (int*)take(128);
    int*   curs   = (int*)take(64);

    // 1) casts into unified [17,...] weight arrays (slot 16 = shared expert)
    cast4<<<8192,  256, 0, stream>>>(x,    x_h, 2097152);
    cast4<<<16384, 256, 0, stream>>>(wgu,  wguA, 4194304);
    cast4<<<1024,  256, 0, stream>>>(wsgu, wguA + (size_t)16 * 1024 * 1024, 262144);
    cast4<<<8192,  256, 0, stream>>>(wd,   wdA, 2097152);
    cast4<<<512,   256, 0, stream>>>(wsd,  wdA + (size_t)16 * 1024 * 512, 131072);
    hipMemcpyAsync(biasA, bgu, (size_t)16 * 1024 * 4, hipMemcpyDeviceToDevice, stream);
    hipMemcpyAsync(biasA + 16 * 1024, bsgu, 1024 * 4, hipMemcpyDeviceToDevice, stream);

    // 2) routing
    zero_counts<<<1, 16, 0, stream>>>(counts);
    router_kernel<<<T_TOK / 4, 256, 0, stream>>>(x, gw, sel, rw, counts);
    prefix_kernel<<<1, 64, 0, stream>>>(counts, offs, curs);
    scatter_kernel<<<T_TOK / 256, 256, 0, stream>>>(sel, rw, curs, btok, bw, pos);

    // 3) gate_up GEMM over all 24576 slots (17 experts incl. shared)
    gemm_gateup<<<dim3(64, 8, N_ALL), 256, 0, stream>>>(x_h, wguA, biasA, gu, offs, btok);

    // 4) SiLU*up with routing weight
    act_kernel<<<NSLOT_ALL / 2, 256, 0, stream>>>(gu, bw, act);

    // 5) down GEMM: plain f16 per-slot stores (no atomics); DOWN aliases gu
    gemm_down<<<dim3(64, 8, N_ALL), 256, 0, stream>>>(act, wdA, down, offs);

    // 6) combine: shared + two routed slots per token
    combine_kernel<<<T_TOK * 1024 / 4 / 256, 256, 0, stream>>>(down, pos, out);
}

// Round 4
// 578.266 us; speedup vs baseline: 1.6816x; 1.3141x over previous
//
#include <hip/hip_runtime.h>
#include <hip/hip_bf16.h>
#include <cstdint>
#include <cstddef>

// ---------------- types ----------------
typedef _Float16 f16;
typedef _Float16 f16x4 __attribute__((ext_vector_type(4)));
typedef _Float16 f16x8 __attribute__((ext_vector_type(8)));
typedef float f32x4 __attribute__((ext_vector_type(4)));

#define GPTR(p) ((const __attribute__((address_space(1))) void*)(p))
#define LPTR(p) ((__attribute__((address_space(3))) void*)(p))

// Problem constants
#define T_TOK 8192
#define H_DIM 1024
#define I_DIM 512
#define N_EXP 16          // routed experts; expert 16 = shared (weight 1.0, all tokens)
#define N_ALL 17
#define TOPK 2
#define NSLOT (T_TOK * TOPK)          // 16384 routed slots
#define NSLOT_ALL (NSLOT + T_TOK)     // 24576 incl. shared

// ---------------- f32 -> f16 cast (4 elems/thread) ----------------
__global__ void cast4(const float* __restrict__ in, f16* __restrict__ out, int n4) {
    int i = blockIdx.x * blockDim.x + threadIdx.x;
    if (i >= n4) return;
    float4 v = ((const float4*)in)[i];
    f16x4 o = { (f16)v.x, (f16)v.y, (f16)v.z, (f16)v.w };
    *(f16x4*)(out + (size_t)i * 4) = o;
}

// ---------------- f32 -> (hi f16, lo f16) split cast: hi+lo carries ~22 mantissa bits ----
__global__ void cast_split(const float* __restrict__ in, f16* __restrict__ hi,
                           f16* __restrict__ lo, int n4) {
    int i = blockIdx.x * blockDim.x + threadIdx.x;
    if (i >= n4) return;
    float4 v = ((const float4*)in)[i];
    float vv[4] = { v.x, v.y, v.z, v.w };
    f16x4 h, l;
#pragma unroll
    for (int r = 0; r < 4; r++) {
        f16 hv = (f16)vv[r];
        h[r] = hv;
        l[r] = (f16)(vv[r] - (float)hv);
    }
    *(f16x4*)(hi + (size_t)i * 4) = h;
    *(f16x4*)(lo + (size_t)i * 4) = l;
}

__global__ void zero_counts(int* counts) { counts[threadIdx.x] = 0; }

// ---------------- router logits via compensated MFMA: L = x @ gw^T in ~f32 precision ----
// logits = xh.gh + xh.gl + xl.gh  (xl.gl term ~1e-7, dropped).
// one wave per 16 tokens; same A.B^T fragment pattern as the big GEMMs.
__global__ __launch_bounds__(256) void logits_kernel(
    const f16* __restrict__ Xh, const f16* __restrict__ Xl,
    const f16* __restrict__ Gh, const f16* __restrict__ Gl,
    float* __restrict__ L) {
    const int wave = threadIdx.x >> 6, lane = threadIdx.x & 63;
    const int m0 = blockIdx.x * 64 + wave * 16;
    const int qm = lane & 15, quad = lane >> 4;
    const size_t arow = (size_t)(m0 + qm) * H_DIM + quad * 8;
    const size_t brow = (size_t)qm * H_DIM + quad * 8;
    f32x4 acc = (f32x4){0.f, 0.f, 0.f, 0.f};
    const f16* ap;
    const f16* bp;
    ap = Xh + arow; bp = Gh + brow;
#pragma unroll 8
    for (int k0 = 0; k0 < H_DIM; k0 += 32) {
        acc = __builtin_amdgcn_mfma_f32_16x16x32_f16(*(const f16x8*)ap, *(const f16x8*)bp, acc, 0, 0, 0);
        ap += 32; bp += 32;
    }
    ap = Xh + arow; bp = Gl + brow;
#pragma unroll 8
    for (int k0 = 0; k0 < H_DIM; k0 += 32) {
        acc = __builtin_amdgcn_mfma_f32_16x16x32_f16(*(const f16x8*)ap, *(const f16x8*)bp, acc, 0, 0, 0);
        ap += 32; bp += 32;
    }
    ap = Xl + arow; bp = Gh + brow;
#pragma unroll 8
    for (int k0 = 0; k0 < H_DIM; k0 += 32) {
        acc = __builtin_amdgcn_mfma_f32_16x16x32_f16(*(const f16x8*)ap, *(const f16x8*)bp, acc, 0, 0, 0);
        ap += 32; bp += 32;
    }
    // C/D: col(expert)=lane&15, row(token)=quad*4+r
#pragma unroll
    for (int r = 0; r < 4; r++)
        L[(size_t)(m0 + quad * 4 + r) * N_EXP + qm] = acc[r];
}

// ---------------- top-2 + renorm weight + LDS histogram ----------------
__global__ void topk_kernel(const float* __restrict__ L, int* __restrict__ sel,
                            float* __restrict__ rw, int* __restrict__ counts) {
    __shared__ int lc[N_EXP];
    const int tid = threadIdx.x;
    if (tid < N_EXP) lc[tid] = 0;
    __syncthreads();
    const int t = blockIdx.x * 256 + tid;
    float lg[16];
    const float4* lp = (const float4*)(L + (size_t)t * N_EXP);
#pragma unroll
    for (int q = 0; q < 4; q++) {
        float4 v = lp[q];
        lg[q * 4 + 0] = v.x; lg[q * 4 + 1] = v.y; lg[q * 4 + 2] = v.z; lg[q * 4 + 3] = v.w;
    }
    float best = -1e30f, sec = -1e30f; int bi = 0, si = 0;
#pragma unroll
    for (int j = 0; j < 16; j++) {
        float lj = lg[j];
        if (lj > best) { sec = best; si = bi; best = lj; bi = j; }
        else if (lj > sec) { sec = lj; si = j; }
    }
    float w1 = 1.f / (1.f + __expf(sec - best));   // renormalized top-2 softmax
    sel[t * 2] = bi; sel[t * 2 + 1] = si;
    rw[t * 2] = w1;  rw[t * 2 + 1] = 1.f - w1;
    atomicAdd(&lc[bi], 1);
    atomicAdd(&lc[si], 1);
    __syncthreads();
    if (tid < N_EXP) atomicAdd(&counts[tid], lc[tid]);
}

__global__ void prefix_kernel(const int* __restrict__ counts, int* __restrict__ offsets,
                              int* __restrict__ cursors) {
    if (threadIdx.x == 0) {
        int s = 0;
        for (int e = 0; e < N_EXP; e++) { offsets[e] = s; cursors[e] = s; s += counts[e]; }
        offsets[N_EXP] = s;                 // 16384
        offsets[N_EXP + 1] = s + T_TOK;     // 24576 (shared bucket)
    }
}

// scatter routed slots + build the identity shared bucket; record slot pos per (t,k)
__global__ void scatter_kernel(const int* __restrict__ sel, const float* __restrict__ rw,
                               int* __restrict__ cursors, int* __restrict__ btok,
                               float* __restrict__ bw, int* __restrict__ pos) {
    int t = blockIdx.x * blockDim.x + threadIdx.x;
    if (t >= T_TOK) return;
#pragma unroll
    for (int k = 0; k < TOPK; k++) {
        int e = sel[t * 2 + k];
        int p = atomicAdd(&cursors[e], 1);
        btok[p] = t;
        bw[p] = rw[t * 2 + k];
        pos[t * 2 + k] = p;
    }
    btok[NSLOT + t] = t;     // shared bucket: identity
    bw[NSLOT + t] = 1.f;
}

// ---------------- gate_up GEMM: GU[slot, 0:1024] = X[btok[slot]] @ W_e^T + bias_e ----------
__global__ __launch_bounds__(256) void gemm_gateup(
    const f16* __restrict__ X,        // [T,1024] f16
    const f16* __restrict__ W,        // [17,1024,1024] f16
    const float* __restrict__ bias,   // [17,1024] f32
    f16* __restrict__ GU,             // [24576,1024] f16
    const int* __restrict__ offsets,  // [18]
    const int* __restrict__ btok) {
    constexpr int K = H_DIM;
    const int e  = blockIdx.z;
    const int m0 = blockIdx.x * 128;
    const int n0 = blockIdx.y * 128;
    const int base = offsets[e];
    const int M = offsets[e + 1] - base;
    if (m0 >= M) return;

    const f16* Wb   = W + (size_t)e * 1024 * K;
    const float* bb = bias + (size_t)e * 1024;

    __shared__ f16 As[128 * 32];
    __shared__ f16 Bs[128 * 32];

    const int tid  = threadIdx.x;
    const int wave = tid >> 6;
    const int lane = tid & 63;
    const int srow = lane >> 2;          // 0..15
    const int scol = (lane & 3) * 8;     // 0,8,16,24

    int ar0 = m0 + wave * 32 + srow;
    int ar1 = ar0 + 16;
    int r0 = min(ar0, M - 1), r1 = min(ar1, M - 1);
    const f16* ap0 = X + (size_t)btok[base + r0] * K + scol;
    const f16* ap1 = X + (size_t)btok[base + r1] * K + scol;
    const f16* bp0 = Wb + (size_t)(n0 + wave * 32 + srow) * K + scol;
    const f16* bp1 = bp0 + (size_t)16 * K;
    f16* la0 = &As[(wave * 32) * 32];
    f16* la1 = &As[(wave * 32 + 16) * 32];
    f16* lb0 = &Bs[(wave * 32) * 32];
    f16* lb1 = &Bs[(wave * 32 + 16) * 32];

    const int wm = (wave >> 1) * 64;
    const int wn = (wave & 1) * 64;
    const int qm = lane & 15;
    const int quad = lane >> 4;

    f32x4 acc[4][4];
#pragma unroll
    for (int i = 0; i < 4; i++)
#pragma unroll
        for (int j = 0; j < 4; j++) acc[i][j] = (f32x4){0.f, 0.f, 0.f, 0.f};

    for (int k0 = 0; k0 < K; k0 += 32) {
        __builtin_amdgcn_global_load_lds(GPTR(ap0), LPTR(la0), 16, 0, 0);
        __builtin_amdgcn_global_load_lds(GPTR(ap1), LPTR(la1), 16, 0, 0);
        __builtin_amdgcn_global_load_lds(GPTR(bp0), LPTR(lb0), 16, 0, 0);
        __builtin_amdgcn_global_load_lds(GPTR(bp1), LPTR(lb1), 16, 0, 0);
        ap0 += 32; ap1 += 32; bp0 += 32; bp1 += 32;
        __syncthreads();
        f16x8 af[4], bfr[4];
#pragma unroll
        for (int i = 0; i < 4; i++) af[i]  = *(const f16x8*)&As[(wm + i * 16 + qm) * 32 + quad * 8];
#pragma unroll
        for (int j = 0; j < 4; j++) bfr[j] = *(const f16x8*)&Bs[(wn + j * 16 + qm) * 32 + quad * 8];
#pragma unroll
        for (int i = 0; i < 4; i++)
#pragma unroll
            for (int j = 0; j < 4; j++)
                acc[i][j] = __builtin_amdgcn_mfma_f32_16x16x32_f16(af[i], bfr[j], acc[i][j], 0, 0, 0);
        __syncthreads();
    }

    // C/D mapping: col = lane&15, row = quad*4 + reg
#pragma unroll
    for (int i = 0; i < 4; i++) {
#pragma unroll
        for (int j = 0; j < 4; j++) {
            const int col = n0 + wn + j * 16 + qm;
            const float bv = bb[col];
#pragma unroll
            for (int r = 0; r < 4; r++) {
                const int lr = wm + i * 16 + quad * 4 + r;
                const int m = m0 + lr;
                if (m < M) GU[(size_t)(base + m) * 1024 + col] = (f16)(acc[i][j][r] + bv);
            }
        }
    }
}

// ---------------- SiLU(g)*u * routing_weight ----------------
__global__ void act_kernel(const f16* __restrict__ GU, const float* __restrict__ bw,
                           f16* __restrict__ ACT) {
    int idx = blockIdx.x * blockDim.x + threadIdx.x;
    int s = idx >> 7;              // 128 threads per slot (512 cols / 4)
    int c = (idx & 127) * 4;
    float scale = bw[s];
    const f16* g = GU + (size_t)s * 1024;
    f16x4 gv = *(const f16x4*)(g + c);
    f16x4 uv = *(const f16x4*)(g + 512 + c);
    f16x4 o;
#pragma unroll
    for (int r = 0; r < 4; r++) {
        float gg = (float)gv[r], uu = (float)uv[r];
        float sl = gg / (1.f + __expf(-gg));
        o[r] = (f16)(sl * uu * scale);
    }
    *(f16x4*)(ACT + (size_t)s * 512 + c) = o;
}

// ---------------- down GEMM: DOWN[slot, 0:1024] = ACT[slot] @ Wd_e^T (plain f16 store) ----
__global__ __launch_bounds__(256) void gemm_down(
    const f16* __restrict__ ACT,      // [24576,512]
    const f16* __restrict__ W,        // [17,1024,512]
    f16* __restrict__ DOWN,           // [24576,1024]
    const int* __restrict__ offsets) {
    constexpr int K = I_DIM;  // 512
    const int e  = blockIdx.z;
    const int m0 = blockIdx.x * 128;
    const int n0 = blockIdx.y * 128;
    const int base = offsets[e];
    const int M = offsets[e + 1] - base;
    if (m0 >= M) return;

    const f16* Wb = W + (size_t)e * 1024 * K;

    __shared__ f16 As[128 * 32];
    __shared__ f16 Bs[128 * 32];

    const int tid  = threadIdx.x;
    const int wave = tid >> 6;
    const int lane = tid & 63;
    const int srow = lane >> 2;
    const int scol = (lane & 3) * 8;

    int ar0 = m0 + wave * 32 + srow;
    int ar1 = ar0 + 16;
    int r0 = min(ar0, M - 1), r1 = min(ar1, M - 1);
    const f16* ap0 = ACT + (size_t)(base + r0) * K + scol;
    const f16* ap1 = ACT + (size_t)(base + r1) * K + scol;
    const f16* bp0 = Wb + (size_t)(n0 + wave * 32 + srow) * K + scol;
    const f16* bp1 = bp0 + (size_t)16 * K;
    f16* la0 = &As[(wave * 32) * 32];
    f16* la1 = &As[(wave * 32 + 16) * 32];
    f16* lb0 = &Bs[(wave * 32) * 32];
    f16* lb1 = &Bs[(wave * 32 + 16) * 32];

    const int wm = (wave >> 1) * 64;
    const int wn = (wave & 1) * 64;
    const int qm = lane & 15;
    const int quad = lane >> 4;

    f32x4 acc[4][4];
#pragma unroll
    for (int i = 0; i < 4; i++)
#pragma unroll
        for (int j = 0; j < 4; j++) acc[i][j] = (f32x4){0.f, 0.f, 0.f, 0.f};

    for (int k0 = 0; k0 < K; k0 += 32) {
        __builtin_amdgcn_global_load_lds(GPTR(ap0), LPTR(la0), 16, 0, 0);
        __builtin_amdgcn_global_load_lds(GPTR(ap1), LPTR(la1), 16, 0, 0);
        __builtin_amdgcn_global_load_lds(GPTR(bp0), LPTR(lb0), 16, 0, 0);
        __builtin_amdgcn_global_load_lds(GPTR(bp1), LPTR(lb1), 16, 0, 0);
        ap0 += 32; ap1 += 32; bp0 += 32; bp1 += 32;
        __syncthreads();
        f16x8 af[4], bfr[4];
#pragma unroll
        for (int i = 0; i < 4; i++) af[i]  = *(const f16x8*)&As[(wm + i * 16 + qm) * 32 + quad * 8];
#pragma unroll
        for (int j = 0; j < 4; j++) bfr[j] = *(const f16x8*)&Bs[(wn + j * 16 + qm) * 32 + quad * 8];
#pragma unroll
        for (int i = 0; i < 4; i++)
#pragma unroll
            for (int j = 0; j < 4; j++)
                acc[i][j] = __builtin_amdgcn_mfma_f32_16x16x32_f16(af[i], bfr[j], acc[i][j], 0, 0, 0);
        __syncthreads();
    }

#pragma unroll
    for (int i = 0; i < 4; i++) {
#pragma unroll
        for (int j = 0; j < 4; j++) {
            const int col = n0 + wn + j * 16 + qm;
#pragma unroll
            for (int r = 0; r < 4; r++) {
                const int lr = wm + i * 16 + quad * 4 + r;
                const int m = m0 + lr;
                if (m < M) DOWN[(size_t)(base + m) * 1024 + col] = (f16)acc[i][j][r];
            }
        }
    }
}

// ---------------- combine: out[t] = DOWN[16384+t] + DOWN[p1] + DOWN[p2] ----------------
__global__ void combine_kernel(const f16* __restrict__ DOWN, const int* __restrict__ pos,
                               float* __restrict__ OUT) {
    int idx = blockIdx.x * blockDim.x + threadIdx.x;
    int t = idx >> 8;             // 256 threads per token (1024 cols / 4)
    int c = (idx & 255) * 4;
    int p1 = pos[t * 2], p2 = pos[t * 2 + 1];
    f16x4 a = *(const f16x4*)(DOWN + (size_t)(NSLOT + t) * 1024 + c);
    f16x4 b = *(const f16x4*)(DOWN + (size_t)p1 * 1024 + c);
    f16x4 d = *(const f16x4*)(DOWN + (size_t)p2 * 1024 + c);
    float4 o;
    o.x = (float)a[0] + (float)b[0] + (float)d[0];
    o.y = (float)a[1] + (float)b[1] + (float)d[1];
    o.z = (float)a[2] + (float)b[2] + (float)d[2];
    o.w = (float)a[3] + (float)b[3] + (float)d[3];
    *(float4*)(OUT + (size_t)t * 1024 + c) = o;
}

// ---------------- host launch ----------------
extern "C" void kernel_launch(void* const* d_in, const int* in_sizes, int n_in,
                              void* d_out, int out_size, void* d_ws, size_t ws_size,
                              hipStream_t stream) {
    const float* x    = (const float*)d_in[0];   // [8192,1024]
    const float* gw   = (const float*)d_in[1];   // [16,1024]
    const float* wgu  = (const float*)d_in[2];   // [16,1024,1024]
    const float* bgu  = (const float*)d_in[3];   // [16,1024]
    const float* wd   = (const float*)d_in[4];   // [16,1024,512]
    const float* wsgu = (const float*)d_in[5];   // [1024,1024]
    const float* bsgu = (const float*)d_in[6];   // [1024]
    const float* wsd  = (const float*)d_in[7];   // [1024,512]
    float* out = (float*)d_out;

    char* ws = (char*)d_ws;
    size_t off = 0;
    auto take = [&](size_t b) { char* p = ws + off; off = (off + b + 255) & ~(size_t)255; return p; };
    f16* x_h    = (f16*)take((size_t)T_TOK * H_DIM * 2);
    f16* x_l    = (f16*)take((size_t)T_TOK * H_DIM * 2);
    f16* gw_h   = (f16*)take((size_t)N_EXP * H_DIM * 2);
    f16* gw_l   = (f16*)take((size_t)N_EXP * H_DIM * 2);
    f16* wguA   = (f16*)take((size_t)N_ALL * 1024 * H_DIM * 2);   // [17,1024,1024]
    f16* wdA    = (f16*)take((size_t)N_ALL * 1024 * I_DIM * 2);   // [17,1024,512]
    float* biasA = (float*)take((size_t)N_ALL * 1024 * 4);        // [17,1024]
    f16* gu     = (f16*)take((size_t)NSLOT_ALL * 1024 * 2);       // [24576,1024]
    f16* act    = (f16*)take((size_t)NSLOT_ALL * I_DIM * 2);      // [24576,512]
    f16* down   = gu;  // alias: gu is dead after act_kernel
    float* logits = (float*)take((size_t)T_TOK * N_EXP * 4);
    int*   sel    = (int*)take((size_t)NSLOT * 4);
    float* rw     = (float*)take((size_t)NSLOT * 4);
    int*   btok   = (int*)take((size_t)NSLOT_ALL * 4);
    float* bw     = (float*)take((size_t)NSLOT_ALL * 4);
    int*   pos    = (int*)take((size_t)NSLOT * 4);
    int*   counts = (int*)take(64);
    int*   offs   = (int*)take(128);
    int*   curs   = (int*)take(64);

    // 1) casts into unified [17,...] weight arrays (slot 16 = shared expert)
    cast_split<<<8192, 256, 0, stream>>>(x,  x_h,  x_l, 2097152);   // hi == cast4(x)
    cast_split<<<16,   256, 0, stream>>>(gw, gw_h, gw_l, 4096);
    cast4<<<16384, 256, 0, stream>>>(wgu,  wguA, 4194304);
    cast4<<<1024,  256, 0, stream>>>(wsgu, wguA + (size_t)16 * 1024 * 1024, 262144);
    cast4<<<8192,  256, 0, stream>>>(wd,   wdA, 2097152);
    cast4<<<512,   256, 0, stream>>>(wsd,  wdA + (size_t)16 * 1024 * 512, 131072);
    hipMemcpyAsync(biasA, bgu, (size_t)16 * 1024 * 4, hipMemcpyDeviceToDevice, stream);
    hipMemcpyAsync(biasA + 16 * 1024, bsgu, 1024 * 4, hipMemcpyDeviceToDevice, stream);

    // 2) routing: compensated MFMA logits -> top2 -> prefix -> scatter
    zero_counts<<<1, 16, 0, stream>>>(counts);
    logits_kernel<<<T_TOK / 64, 256, 0, stream>>>(x_h, x_l, gw_h, gw_l, logits);
    topk_kernel<<<T_TOK / 256, 256, 0, stream>>>(logits, sel, rw, counts);
    prefix_kernel<<<1, 64, 0, stream>>>(counts, offs, curs);
    scatter_kernel<<<T_TOK / 256, 256, 0, stream>>>(sel, rw, curs, btok, bw, pos);

    // 3) gate_up GEMM over all 24576 slots (17 experts incl. shared)
    gemm_gateup<<<dim3(64, 8, N_ALL), 256, 0, stream>>>(x_h, wguA, biasA, gu, offs, btok);

    // 4) SiLU*up with routing weight
    act_kernel<<<NSLOT_ALL / 2, 256, 0, stream>>>(gu, bw, act);

    // 5) down GEMM: plain f16 per-slot stores (no atomics); DOWN aliases gu
    gemm_down<<<dim3(64, 8, N_ALL), 256, 0, stream>>>(act, wdA, down, offs);

    // 6) combine: shared + two routed slots per token
    combine_kernel<<<T_TOK * 1024 / 4 / 256, 256, 0, stream>>>(down, pos, out);
}